// Round 6
// baseline (1004.762 us; speedup 1.0000x reference)
//
#include <hip/hip_runtime.h>
#include <math.h>
#include <type_traits>

// ---------- bf16 helpers (intermediate buffers only; I/O is fp32) ----------

__device__ __forceinline__ float bf2f(unsigned short u) {
    union { unsigned int i; float f; } v; v.i = ((unsigned int)u) << 16; return v.f;
}
__device__ __forceinline__ unsigned short f2bf(float f) {
    union { float f_; unsigned int i; } v; v.f_ = f;
    unsigned int x = v.i;
    return (unsigned short)((x + 0x7fffu + ((x >> 16) & 1u)) >> 16);  // RNE
}
__device__ __forceinline__ float sigm(float x) { return 1.f / (1.f + expf(-x)); }

typedef __attribute__((ext_vector_type(8))) short short8;
typedef __attribute__((ext_vector_type(4))) float f32x4;

// ---------------- CSR build ----------------

__global__ void k_count(const int* __restrict__ dst, int* __restrict__ indeg, int E) {
    int i = blockIdx.x * 256 + threadIdx.x;
    if (i < E) atomicAdd(&indeg[dst[i]], 1);
}

__global__ void k_dinv(const int* __restrict__ indeg, float* __restrict__ dinv, int N) {
    int i = blockIdx.x * 256 + threadIdx.x;
    if (i < N) dinv[i] = rsqrtf((float)indeg[i] + 1.0f);
}

__global__ __launch_bounds__(1024) void k_scan1(const int* __restrict__ in, int* __restrict__ out,
                                                int* __restrict__ bsum, int N) {
    __shared__ int sd[1024];
    int tid = threadIdx.x;
    int i = blockIdx.x * 1024 + tid;
    int v = (i < N) ? in[i] : 0;
    sd[tid] = v;
    __syncthreads();
    for (int s = 1; s < 1024; s <<= 1) {
        int t = (tid >= s) ? sd[tid - s] : 0;
        __syncthreads();
        sd[tid] += t;
        __syncthreads();
    }
    if (i < N) out[i] = sd[tid] - v;
    if (tid == 1023) bsum[blockIdx.x] = sd[1023];
}

__global__ void k_scan2(int* __restrict__ bsum, int nb) {
    if (threadIdx.x == 0 && blockIdx.x == 0) {
        int acc = 0;
        for (int b = 0; b < nb; ++b) { int t = bsum[b]; bsum[b] = acc; acc += t; }
        bsum[nb] = acc;
    }
}

__global__ __launch_bounds__(1024) void k_scan3(int* __restrict__ off, const int* __restrict__ bsum,
                                                int N, int nb) {
    int i = blockIdx.x * 1024 + threadIdx.x;
    if (i < N) off[i] += bsum[i >> 10];
    else if (i == N) off[N] = bsum[nb];
}

__global__ void k_fill(const int* __restrict__ src, const int* __restrict__ dst,
                       const float* __restrict__ dinv, const int* __restrict__ off,
                       int* __restrict__ cursor, int* __restrict__ csrc,
                       float* __restrict__ cw, int E) {
    int i = blockIdx.x * 256 + threadIdx.x;
    if (i >= E) return;
    int d = dst[i], s = src[i];
    int p = off[d] + atomicAdd(&cursor[d], 1);
    csrc[p] = s;
    cw[p] = dinv[s] * dinv[d];
}

// ---------------- weight transpose+convert: Wt[n][k] = bf16(W[k][n]) ----------------

__global__ void k_transpose(const float* __restrict__ W, unsigned short* __restrict__ Wt,
                            int K, int Nc) {
    int i = blockIdx.x * 256 + threadIdx.x;
    if (i < K * Nc) {
        int k = i / Nc, n = i - k * Nc;
        Wt[(size_t)n * K + k] = f2bf(W[i]);
    }
}

// ---------------- fused GCN layer: aggregate -> LDS A-tile -> MFMA GEMM ----------------
// Hout = relu( (D^-1/2 (A+I) D^-1/2) Hin @ W + b )
// One block per 64-node stripe. Phase A: each wave aggregates its 16 nodes
// (8-deep edge prefetch for MLP) into LDS tile sA[64][K+8] (bf16, padded:
// row stride = (K+8)*2 B -> 4-bank shift/row -> 2-way conflict = free).
// Phase B: A-stationary MFMA over all NC column tiles, A-frags from LDS.
// POOL=1: relu + LDS pool over rows (batch sorted; <=2 graphs/stripe fast path),
// then global atomic flush.  A-frag: A[m=lane&15][k=(lane>>4)*8+j];
// B-frag: Wt[n=lane&15][same k]; C/D: col=lane&15, row=(lane>>4)*4+reg.

template <int K, int NC, int POOL, typename T>
__global__ __launch_bounds__(256) void k_fused(
        const T* __restrict__ Hin, const float* __restrict__ dinv,
        const int* __restrict__ off, const int* __restrict__ csrc,
        const float* __restrict__ cw,
        const unsigned short* __restrict__ Wt, const float* __restrict__ bias,
        unsigned short* __restrict__ Hout, float* __restrict__ pooled,
        const int* __restrict__ batch, int N) {
    constexpr int PITCH = K + 8;
    constexpr int KST = K / 32;
    constexpr int NT = NC / 64;
    constexpr int R = (K >= 256) ? 4 : (K >= 128 ? 2 : 1);
    __shared__ unsigned short sA[64 * PITCH];
    __shared__ float pacc[POOL ? 2 : 1][POOL ? NC : 1];
    __shared__ int sbat[POOL ? 64 : 1];

    int tid = threadIdx.x;
    int lane = tid & 63, wv = tid >> 6;
    int r = lane & 15, q = lane >> 4;
    int rowB0 = blockIdx.x * 64;

    if (POOL) {
        if (tid < 64) { int rr = rowB0 + tid; if (rr > N - 1) rr = N - 1; sbat[tid] = batch[rr]; }
        for (int i = tid; i < 2 * NC; i += 256) pacc[i / NC][i % NC] = 0.f;
    }

    // ---- phase A: aggregate ----
    int fb = lane * R;
    bool act = fb < K;            // K=32: lanes 32..63 idle
    #pragma unroll 1
    for (int i = 0; i < 16; ++i) {
        int node = rowB0 + wv * 16 + i;
        float acc[R];
        #pragma unroll
        for (int j = 0; j < R; ++j) acc[j] = 0.f;
        if (node < N && act) {
            float dn = dinv[node], sn = dn * dn;
            const T* ps = Hin + (size_t)node * K + fb;
            if constexpr (std::is_same_v<T, float>) {
                acc[0] = ps[0] * sn;
            } else if constexpr (R == 4) {
                ushort4 hv = *(const ushort4*)ps;
                acc[0] = bf2f(hv.x) * sn; acc[1] = bf2f(hv.y) * sn;
                acc[2] = bf2f(hv.z) * sn; acc[3] = bf2f(hv.w) * sn;
            } else {
                ushort2 hv = *(const ushort2*)ps;
                acc[0] = bf2f(hv.x) * sn; acc[1] = bf2f(hv.y) * sn;
            }
            int s0 = off[node], s1 = off[node + 1];
            for (int e = s0; e < s1; e += 8) {
                int cnt = s1 - e; if (cnt > 8) cnt = 8;
                int idx[8]; float wgt[8];
                #pragma unroll
                for (int j = 0; j < 8; ++j) {
                    int ee = e + ((j < cnt) ? j : 0);
                    idx[j] = csrc[ee];
                    wgt[j] = cw[ee];
                }
                #pragma unroll
                for (int j = 0; j < 8; ++j) {
                    if (j < cnt) {
                        const T* p = Hin + (size_t)idx[j] * K + fb;
                        float w = wgt[j];
                        if constexpr (std::is_same_v<T, float>) {
                            acc[0] += p[0] * w;
                        } else if constexpr (R == 4) {
                            ushort4 hv = *(const ushort4*)p;
                            acc[0] += bf2f(hv.x) * w; acc[1] += bf2f(hv.y) * w;
                            acc[2] += bf2f(hv.z) * w; acc[3] += bf2f(hv.w) * w;
                        } else {
                            ushort2 hv = *(const ushort2*)p;
                            acc[0] += bf2f(hv.x) * w; acc[1] += bf2f(hv.y) * w;
                        }
                    }
                }
            }
        }
        if (act) {
            unsigned short* pd = &sA[(wv * 16 + i) * PITCH + fb];
            if constexpr (R == 4) {
                ushort4 o; o.x = f2bf(acc[0]); o.y = f2bf(acc[1]);
                o.z = f2bf(acc[2]); o.w = f2bf(acc[3]);
                *(ushort4*)pd = o;
            } else if constexpr (R == 2) {
                ushort2 o; o.x = f2bf(acc[0]); o.y = f2bf(acc[1]);
                *(ushort2*)pd = o;
            } else {
                pd[0] = f2bf(acc[0]);
            }
        }
    }
    __syncthreads();

    // ---- phase B: A-stationary MFMA GEMM ----
    int row0 = rowB0 + wv * 16;
    short8 aF[KST];
    #pragma unroll
    for (int kc = 0; kc < KST; ++kc)
        aF[kc] = *(const short8*)&sA[(wv * 16 + r) * PITCH + kc * 32 + q * 8];

    int gmin = 0; bool fast = false;
    if (POOL) { gmin = sbat[0]; fast = (sbat[63] - gmin) <= 1; }

    for (int t = 0; t < NT; ++t) {
        int col0 = t * 64;
        const short8* Bp0 = (const short8*)(Wt + (size_t)(col0 +  0 + r) * K) + q;
        const short8* Bp1 = (const short8*)(Wt + (size_t)(col0 + 16 + r) * K) + q;
        const short8* Bp2 = (const short8*)(Wt + (size_t)(col0 + 32 + r) * K) + q;
        const short8* Bp3 = (const short8*)(Wt + (size_t)(col0 + 48 + r) * K) + q;
        f32x4 acc[4] = {{0.f,0.f,0.f,0.f},{0.f,0.f,0.f,0.f},{0.f,0.f,0.f,0.f},{0.f,0.f,0.f,0.f}};
        #pragma unroll
        for (int kc = 0; kc < KST; ++kc) {
            acc[0] = __builtin_amdgcn_mfma_f32_16x16x32_bf16(aF[kc], Bp0[kc * 4], acc[0], 0, 0, 0);
            acc[1] = __builtin_amdgcn_mfma_f32_16x16x32_bf16(aF[kc], Bp1[kc * 4], acc[1], 0, 0, 0);
            acc[2] = __builtin_amdgcn_mfma_f32_16x16x32_bf16(aF[kc], Bp2[kc * 4], acc[2], 0, 0, 0);
            acc[3] = __builtin_amdgcn_mfma_f32_16x16x32_bf16(aF[kc], Bp3[kc * 4], acc[3], 0, 0, 0);
        }
        #pragma unroll
        for (int tt = 0; tt < 4; ++tt) {
            int col = col0 + tt * 16 + r;
            float bv = bias[col];
            #pragma unroll
            for (int j = 0; j < 4; ++j) {
                int row = row0 + q * 4 + j;
                if (row < N) {
                    float v = fmaxf(acc[tt][j] + bv, 0.f);
                    if (POOL) {
                        int g = sbat[row - rowB0];
                        if (fast) atomicAdd(&pacc[g - gmin][col], v);
                        else      atomicAdd(&pooled[(size_t)g * NC + col], v);
                    } else {
                        Hout[(size_t)row * NC + col] = f2bf(v);
                    }
                }
            }
        }
    }
    if (POOL) {
        __syncthreads();
        if (fast) {
            for (int i = tid; i < 2 * NC; i += 256) {
                int gg = i / NC, col = i % NC;
                if (gmin + gg < 64 || gg == 0)
                    atomicAdd(&pooled[(size_t)(gmin + gg) * NC + col], pacc[gg][col]);
            }
        }
    }
}

// ---------------- graph segment bounds (batch sorted) ----------------

__global__ void k_bounds(const int* __restrict__ batch, int* __restrict__ gstart,
                         int* __restrict__ gend, int N) {
    int i = blockIdx.x * 256 + threadIdx.x;
    if (i >= N) return;
    int g = batch[i];
    if (i == 0 || batch[i - 1] != g) gstart[g] = i;
    if (i == N - 1 || batch[i + 1] != g) gend[g] = i + 1;
}

// ---------------- fused head (all fp32): mean + LSTM0 + LSTM1 + projection ----------------
// h0=c0=0 => gates = x @ Wih.T + bih + bhh; f-gate dead; c = i*g; h = o*tanh(c)

__device__ __forceinline__ float dotf(const float* __restrict__ w,
                                      const float* __restrict__ x, int K) {
    float a = 0.f;
    for (int k = 0; k < K; k += 4) {
        float4 wv = *(const float4*)(w + k);
        a += wv.x * x[k] + wv.y * x[k + 1] + wv.z * x[k + 2] + wv.w * x[k + 3];
    }
    return a;
}

__global__ __launch_bounds__(256) void k_head(
        const float* __restrict__ pooledSum,
        const int* __restrict__ gstart, const int* __restrict__ gend,
        const float* __restrict__ Wih0, const float* __restrict__ bih0,
        const float* __restrict__ bhh0,
        const float* __restrict__ Wih1, const float* __restrict__ bih1,
        const float* __restrict__ bhh1,
        const float* __restrict__ Wp, const float* __restrict__ bp,
        float* __restrict__ out) {
    __shared__ float sx[512];
    __shared__ float sh[256];
    int g = blockIdx.x, tid = threadIdx.x;
    float cnt = (float)(gend[g] - gstart[g]);
    float inv = 1.f / fmaxf(cnt, 1.f);
    sx[tid]       = pooledSum[g * 512 + tid] * inv;
    sx[tid + 256] = pooledSum[g * 512 + 256 + tid] * inv;
    __syncthreads();

    float ai = bih0[tid]       + bhh0[tid];
    float ag = bih0[tid + 512] + bhh0[tid + 512];
    float ao = bih0[tid + 768] + bhh0[tid + 768];
    ai += dotf(Wih0 + (size_t)tid * 512, sx, 512);
    ag += dotf(Wih0 + (size_t)(tid + 512) * 512, sx, 512);
    ao += dotf(Wih0 + (size_t)(tid + 768) * 512, sx, 512);
    float c0 = sigm(ai) * tanhf(ag);
    float h1 = sigm(ao) * tanhf(c0);
    __syncthreads();
    sh[tid] = h1;
    __syncthreads();

    ai = bih1[tid]       + bhh1[tid];
    ag = bih1[tid + 512] + bhh1[tid + 512];
    ao = bih1[tid + 768] + bhh1[tid + 768];
    ai += dotf(Wih1 + (size_t)tid * 256, sh, 256);
    ag += dotf(Wih1 + (size_t)(tid + 512) * 256, sh, 256);
    ao += dotf(Wih1 + (size_t)(tid + 768) * 256, sh, 256);
    float c1 = sigm(ai) * tanhf(ag);
    float h2 = sigm(ao) * tanhf(c1);
    __syncthreads();
    sx[tid] = h2;
    __syncthreads();

    float o0 = bp[tid]       + dotf(Wp + (size_t)tid * 256, sx, 256);
    float o1 = bp[tid + 256] + dotf(Wp + (size_t)(tid + 256) * 256, sx, 256);
    out[g * 512 + tid]       = o0;
    out[g * 512 + 256 + tid] = o1;
}

// ---------------- launch ----------------

extern "C" void kernel_launch(void* const* d_in, const int* in_sizes, int n_in,
                              void* d_out, int out_size, void* d_ws, size_t ws_size,
                              hipStream_t stream) {
    const float* x     = (const float*)d_in[0];
    const int*   eidx  = (const int*)d_in[1];
    const int*   batch = (const int*)d_in[2];
    const float* W1 = (const float*)d_in[3];  const float* b1 = (const float*)d_in[4];
    const float* W2 = (const float*)d_in[5];  const float* b2 = (const float*)d_in[6];
    const float* W3 = (const float*)d_in[7];  const float* b3 = (const float*)d_in[8];
    const float* Wih0 = (const float*)d_in[9];
    const float* bih0 = (const float*)d_in[11];
    const float* bhh0 = (const float*)d_in[12];
    const float* Wih1 = (const float*)d_in[13];
    const float* bih1 = (const float*)d_in[15];
    const float* bhh1 = (const float*)d_in[16];
    const float* Wp = (const float*)d_in[17]; const float* bp = (const float*)d_in[18];
    float* out = (float*)d_out;

    const int N = in_sizes[0] / 32;
    const int E = in_sizes[1] / 2;
    const int* src = eidx;
    const int* dst = eidx + E;

    char* w = (char*)d_ws;
    auto alloc = [&](size_t bytes) {
        char* p = w;
        w += (bytes + 255) & ~(size_t)255;
        return p;
    };
    unsigned short* buf1 = (unsigned short*)alloc((size_t)N * 256 * 2);   // 51.2 MB
    unsigned short* buf2 = (unsigned short*)alloc((size_t)N * 256 * 2);   // 51.2 MB
    unsigned short* Wt1  = (unsigned short*)alloc(128 * 32 * 2);
    unsigned short* Wt2  = (unsigned short*)alloc(256 * 128 * 2);
    unsigned short* Wt3  = (unsigned short*)alloc(512 * 256 * 2);
    int*   indeg  = (int*)alloc((size_t)N * 4);
    int*   off    = (int*)alloc((size_t)(N + 1) * 4);
    int*   cursor = (int*)alloc((size_t)N * 4);
    float* dinv   = (float*)alloc((size_t)N * 4);
    int*   csrc   = (int*)alloc((size_t)E * 4);
    float* cw     = (float*)alloc((size_t)E * 4);
    int*   bsum   = (int*)alloc(256 * 4);
    int*   gstart = (int*)alloc(64 * 4);
    int*   gend   = (int*)alloc(64 * 4);
    float* pooled = (float*)alloc(64 * 512 * 4);

    hipMemsetAsync(indeg, 0, (size_t)N * 4, stream);
    hipMemsetAsync(cursor, 0, (size_t)N * 4, stream);
    hipMemsetAsync(gstart, 0, 64 * 4, stream);
    hipMemsetAsync(gend, 0, 64 * 4, stream);
    hipMemsetAsync(pooled, 0, 64 * 512 * 4, stream);

    k_count<<<(E + 255) / 256, 256, 0, stream>>>(dst, indeg, E);
    k_dinv<<<(N + 255) / 256, 256, 0, stream>>>(indeg, dinv, N);
    int nb = (N + 1023) / 1024;
    k_scan1<<<nb, 1024, 0, stream>>>(indeg, off, bsum, N);
    k_scan2<<<1, 64, 0, stream>>>(bsum, nb);
    k_scan3<<<(N + 1 + 1023) / 1024, 1024, 0, stream>>>(off, bsum, N, nb);
    k_fill<<<(E + 255) / 256, 256, 0, stream>>>(src, dst, dinv, off, cursor, csrc, cw, E);

    k_transpose<<<(32 * 128 + 255) / 256, 256, 0, stream>>>(W1, Wt1, 32, 128);
    k_transpose<<<(128 * 256 + 255) / 256, 256, 0, stream>>>(W2, Wt2, 128, 256);
    k_transpose<<<(256 * 512 + 255) / 256, 256, 0, stream>>>(W3, Wt3, 256, 512);
    k_bounds<<<(N + 255) / 256, 256, 0, stream>>>(batch, gstart, gend, N);

    int rowTiles = (N + 63) / 64;

    // layer 1: x fp32 [N,32] -> buf2 [N,128] bf16
    k_fused<32, 128, 0, float><<<rowTiles, 256, 0, stream>>>(
        x, dinv, off, csrc, cw, Wt1, b1, buf2, nullptr, nullptr, N);
    // layer 2: buf2 [N,128] -> buf1 [N,256]
    k_fused<128, 256, 0, unsigned short><<<rowTiles, 256, 0, stream>>>(
        buf2, dinv, off, csrc, cw, Wt2, b2, buf1, nullptr, nullptr, N);
    // layer 3: buf1 [N,256] -> pooled [64,512] (relu + mean-pool fused)
    k_fused<256, 512, 1, unsigned short><<<rowTiles, 256, 0, stream>>>(
        buf1, dinv, off, csrc, cw, Wt3, b3, nullptr, pooled, batch, N);

    k_head<<<64, 256, 0, stream>>>(pooled, gstart, gend,
                                   Wih0, bih0, bhh0, Wih1, bih1, bhh1, Wp, bp, out);
}

// Round 7
// 889.755 us; speedup vs baseline: 1.1293x; 1.1293x over previous
//
#include <hip/hip_runtime.h>
#include <math.h>
#include <type_traits>

// ---------- bf16 helpers (intermediate buffers only; I/O is fp32) ----------

__device__ __forceinline__ float bf2f(unsigned short u) {
    union { unsigned int i; float f; } v; v.i = ((unsigned int)u) << 16; return v.f;
}
__device__ __forceinline__ unsigned short f2bf(float f) {
    union { float f_; unsigned int i; } v; v.f_ = f;
    unsigned int x = v.i;
    return (unsigned short)((x + 0x7fffu + ((x >> 16) & 1u)) >> 16);  // RNE
}
__device__ __forceinline__ float sigm(float x) { return 1.f / (1.f + expf(-x)); }

typedef __attribute__((ext_vector_type(8))) short short8;
typedef __attribute__((ext_vector_type(4))) float f32x4;

// ---------------- CSR build ----------------

__global__ void k_count(const int* __restrict__ dst, int* __restrict__ indeg, int E) {
    int i = blockIdx.x * 256 + threadIdx.x;
    if (i < E) atomicAdd(&indeg[dst[i]], 1);
}

__global__ void k_dinv(const int* __restrict__ indeg, float* __restrict__ dinv, int N) {
    int i = blockIdx.x * 256 + threadIdx.x;
    if (i < N) dinv[i] = rsqrtf((float)indeg[i] + 1.0f);
}

__global__ __launch_bounds__(1024) void k_scan1(const int* __restrict__ in, int* __restrict__ out,
                                                int* __restrict__ bsum, int N) {
    __shared__ int sd[1024];
    int tid = threadIdx.x;
    int i = blockIdx.x * 1024 + tid;
    int v = (i < N) ? in[i] : 0;
    sd[tid] = v;
    __syncthreads();
    for (int s = 1; s < 1024; s <<= 1) {
        int t = (tid >= s) ? sd[tid - s] : 0;
        __syncthreads();
        sd[tid] += t;
        __syncthreads();
    }
    if (i < N) out[i] = sd[tid] - v;
    if (tid == 1023) bsum[blockIdx.x] = sd[1023];
}

__global__ void k_scan2(int* __restrict__ bsum, int nb) {
    if (threadIdx.x == 0 && blockIdx.x == 0) {
        int acc = 0;
        for (int b = 0; b < nb; ++b) { int t = bsum[b]; bsum[b] = acc; acc += t; }
        bsum[nb] = acc;
    }
}

__global__ __launch_bounds__(1024) void k_scan3(int* __restrict__ off, const int* __restrict__ bsum,
                                                int N, int nb) {
    int i = blockIdx.x * 1024 + threadIdx.x;
    if (i < N) off[i] += bsum[i >> 10];
    else if (i == N) off[N] = bsum[nb];
}

__global__ void k_fill(const int* __restrict__ src, const int* __restrict__ dst,
                       const float* __restrict__ dinv, const int* __restrict__ off,
                       int* __restrict__ cursor, int* __restrict__ csrc,
                       float* __restrict__ cw, int E) {
    int i = blockIdx.x * 256 + threadIdx.x;
    if (i >= E) return;
    int d = dst[i], s = src[i];
    int p = off[d] + atomicAdd(&cursor[d], 1);
    csrc[p] = s;
    cw[p] = dinv[s] * dinv[d];
}

// ---------------- weight transpose+convert: Wt[n][k] = bf16(W[k][n]) ----------------

__global__ void k_transpose(const float* __restrict__ W, unsigned short* __restrict__ Wt,
                            int K, int Nc) {
    int i = blockIdx.x * 256 + threadIdx.x;
    if (i < K * Nc) {
        int k = i / Nc, n = i - k * Nc;
        Wt[(size_t)n * K + k] = f2bf(W[i]);
    }
}

// ---------------- aggregation v2: one wave per node, branchless 8-deep prefetch ----
// out[n] = dinv[n]^2*H[n] + sum_{e: dst=n} w_e * H[src_e]
// Per 8-edge round: idx/wgt loads (wave-uniform -> SGPR), then ALL 8 row-gathers
// issued unconditionally into distinct registers (tail edges: weight 0, index
// clamped to a valid edge), then consume. 8 independent vmem loads in flight.

template <int F, typename T>
__global__ __launch_bounds__(256) void k_agg2(
        const T* __restrict__ Hin, const float* __restrict__ dinv,
        const int* __restrict__ off, const int* __restrict__ csrc,
        const float* __restrict__ cw, unsigned short* __restrict__ out, int N) {
    constexpr int R = (F >= 256) ? 4 : (F >= 128 ? 2 : 1);
    int wave = (int)((blockIdx.x * 256u + threadIdx.x) >> 6);
    int lane = threadIdx.x & 63;
    if (wave >= N) return;
    int fb = (F >= 64) ? lane * R : lane;
    bool act = fb < F;
    int s0 = off[wave], s1 = off[wave + 1];
    float dn = dinv[wave], sn = dn * dn;
    float acc[R];
    #pragma unroll
    for (int j = 0; j < R; ++j) acc[j] = 0.f;
    if (act) {
        const T* ps = Hin + (size_t)wave * F + fb;
        if constexpr (std::is_same_v<T, float>) {
            acc[0] = ps[0] * sn;
        } else if constexpr (R == 4) {
            ushort4 hv = *(const ushort4*)ps;
            acc[0] = bf2f(hv.x) * sn; acc[1] = bf2f(hv.y) * sn;
            acc[2] = bf2f(hv.z) * sn; acc[3] = bf2f(hv.w) * sn;
        } else {
            ushort2 hv = *(const ushort2*)ps;
            acc[0] = bf2f(hv.x) * sn; acc[1] = bf2f(hv.y) * sn;
        }
    }
    int last = s1 - 1;
    for (int e = s0; e < s1; e += 8) {
        // uniform edge metadata for this round (tail: clamp index, zero weight)
        int   idx[8];
        float wgt[8];
        #pragma unroll
        for (int j = 0; j < 8; ++j) {
            int ee = e + j;
            int ec = ee <= last ? ee : last;
            idx[j] = csrc[ec];
            wgt[j] = (ee <= last) ? cw[ec] : 0.f;
        }
        if (act) {
            if constexpr (std::is_same_v<T, float>) {
                float d0[8];
                #pragma unroll
                for (int j = 0; j < 8; ++j) d0[j] = Hin[(size_t)idx[j] * F + fb];
                #pragma unroll
                for (int j = 0; j < 8; ++j) acc[0] += d0[j] * wgt[j];
            } else if constexpr (R == 4) {
                ushort4 d0[8];
                #pragma unroll
                for (int j = 0; j < 8; ++j)
                    d0[j] = *(const ushort4*)(Hin + (size_t)idx[j] * F + fb);
                #pragma unroll
                for (int j = 0; j < 8; ++j) {
                    float w = wgt[j];
                    acc[0] += bf2f(d0[j].x) * w; acc[1] += bf2f(d0[j].y) * w;
                    acc[2] += bf2f(d0[j].z) * w; acc[3] += bf2f(d0[j].w) * w;
                }
            } else {
                ushort2 d0[8];
                #pragma unroll
                for (int j = 0; j < 8; ++j)
                    d0[j] = *(const ushort2*)(Hin + (size_t)idx[j] * F + fb);
                #pragma unroll
                for (int j = 0; j < 8; ++j) {
                    float w = wgt[j];
                    acc[0] += bf2f(d0[j].x) * w; acc[1] += bf2f(d0[j].y) * w;
                }
            }
        }
    }
    if (act) {
        unsigned short* pd = out + (size_t)wave * F + fb;
        if constexpr (R == 4) {
            ushort4 o; o.x = f2bf(acc[0]); o.y = f2bf(acc[1]);
            o.z = f2bf(acc[2]); o.w = f2bf(acc[3]);
            *(ushort4*)pd = o;
        } else if constexpr (R == 2) {
            ushort2 o; o.x = f2bf(acc[0]); o.y = f2bf(acc[1]);
            *(ushort2*)pd = o;
        } else {
            pd[0] = f2bf(acc[0]);
        }
    }
}

// ---------------- A-stationary MFMA GEMM (round-5 proven) ----------------
// C = relu(A[M,K] @ W[K,NC] + b). One block per 64-row stripe; loops over all
// column tiles with A-fragments register-resident. POOL=1: relu + LDS pool.

template <int K, int NC, int POOL>
__global__ __launch_bounds__(256) void k_gemm(
        const unsigned short* __restrict__ A, const unsigned short* __restrict__ Wt,
        const float* __restrict__ bias, unsigned short* __restrict__ C,
        float* __restrict__ pooled, const int* __restrict__ batch, int M) {
    constexpr int KST = K / 32;
    constexpr int NT = NC / 64;
    __shared__ float pacc[POOL ? 2 : 1][POOL ? NC : 1];
    __shared__ int sbat[POOL ? 64 : 1];
    int tid = threadIdx.x;
    int lane = tid & 63, wv = tid >> 6;
    int r = lane & 15, q = lane >> 4;
    int rowB0 = blockIdx.x * 64;
    int row0 = rowB0 + wv * 16;
    if (POOL) {
        if (tid < 64) {
            int rr = rowB0 + tid; if (rr > M - 1) rr = M - 1;
            sbat[tid] = batch[rr];
        }
        for (int i = tid; i < 2 * NC; i += 256) pacc[i / NC][i % NC] = 0.f;
        __syncthreads();
    }
    int rowA = row0 + r; if (rowA > M - 1) rowA = M - 1;
    const short8* Ap = (const short8*)(A + (size_t)rowA * K) + q;
    short8 aF[KST];
    #pragma unroll
    for (int kc = 0; kc < KST; ++kc) aF[kc] = Ap[kc * 4];

    int gmin = 0; bool fast = false;
    if (POOL) { gmin = sbat[0]; fast = (sbat[63] - gmin) <= 1; }

    for (int t = 0; t < NT; ++t) {
        int col0 = t * 64;
        const short8* Bp0 = (const short8*)(Wt + (size_t)(col0 +  0 + r) * K) + q;
        const short8* Bp1 = (const short8*)(Wt + (size_t)(col0 + 16 + r) * K) + q;
        const short8* Bp2 = (const short8*)(Wt + (size_t)(col0 + 32 + r) * K) + q;
        const short8* Bp3 = (const short8*)(Wt + (size_t)(col0 + 48 + r) * K) + q;
        f32x4 acc[4] = {{0.f,0.f,0.f,0.f},{0.f,0.f,0.f,0.f},{0.f,0.f,0.f,0.f},{0.f,0.f,0.f,0.f}};
        #pragma unroll
        for (int kc = 0; kc < KST; ++kc) {
            acc[0] = __builtin_amdgcn_mfma_f32_16x16x32_bf16(aF[kc], Bp0[kc * 4], acc[0], 0, 0, 0);
            acc[1] = __builtin_amdgcn_mfma_f32_16x16x32_bf16(aF[kc], Bp1[kc * 4], acc[1], 0, 0, 0);
            acc[2] = __builtin_amdgcn_mfma_f32_16x16x32_bf16(aF[kc], Bp2[kc * 4], acc[2], 0, 0, 0);
            acc[3] = __builtin_amdgcn_mfma_f32_16x16x32_bf16(aF[kc], Bp3[kc * 4], acc[3], 0, 0, 0);
        }
        #pragma unroll
        for (int tt = 0; tt < 4; ++tt) {
            int col = col0 + tt * 16 + r;
            float bv = bias[col];
            #pragma unroll
            for (int j = 0; j < 4; ++j) {
                int row = row0 + q * 4 + j;
                if (row < M) {
                    float v = fmaxf(acc[tt][j] + bv, 0.f);
                    if (POOL) {
                        int g = sbat[row - rowB0];
                        if (fast) atomicAdd(&pacc[g - gmin][col], v);
                        else      atomicAdd(&pooled[(size_t)g * NC + col], v);
                    } else {
                        C[(size_t)row * NC + col] = f2bf(v);
                    }
                }
            }
        }
    }
    if (POOL) {
        __syncthreads();
        if (fast) {
            for (int i = tid; i < 2 * NC; i += 256) {
                int gg = i / NC, col = i % NC;
                if (gmin + gg < 64 || gg == 0)
                    atomicAdd(&pooled[(size_t)(gmin + gg) * NC + col], pacc[gg][col]);
            }
        }
    }
}

// ---------------- graph segment bounds (batch sorted) ----------------

__global__ void k_bounds(const int* __restrict__ batch, int* __restrict__ gstart,
                         int* __restrict__ gend, int N) {
    int i = blockIdx.x * 256 + threadIdx.x;
    if (i >= N) return;
    int g = batch[i];
    if (i == 0 || batch[i - 1] != g) gstart[g] = i;
    if (i == N - 1 || batch[i + 1] != g) gend[g] = i + 1;
}

// ---------------- fused head (all fp32): mean + LSTM0 + LSTM1 + projection ----------------
// h0=c0=0 => gates = x @ Wih.T + bih + bhh; f-gate dead; c = i*g; h = o*tanh(c)

__device__ __forceinline__ float dotf(const float* __restrict__ w,
                                      const float* __restrict__ x, int K) {
    float a = 0.f;
    for (int k = 0; k < K; k += 4) {
        float4 wv = *(const float4*)(w + k);
        a += wv.x * x[k] + wv.y * x[k + 1] + wv.z * x[k + 2] + wv.w * x[k + 3];
    }
    return a;
}

__global__ __launch_bounds__(256) void k_head(
        const float* __restrict__ pooledSum,
        const int* __restrict__ gstart, const int* __restrict__ gend,
        const float* __restrict__ Wih0, const float* __restrict__ bih0,
        const float* __restrict__ bhh0,
        const float* __restrict__ Wih1, const float* __restrict__ bih1,
        const float* __restrict__ bhh1,
        const float* __restrict__ Wp, const float* __restrict__ bp,
        float* __restrict__ out) {
    __shared__ float sx[512];
    __shared__ float sh[256];
    int g = blockIdx.x, tid = threadIdx.x;
    float cnt = (float)(gend[g] - gstart[g]);
    float inv = 1.f / fmaxf(cnt, 1.f);
    sx[tid]       = pooledSum[g * 512 + tid] * inv;
    sx[tid + 256] = pooledSum[g * 512 + 256 + tid] * inv;
    __syncthreads();

    float ai = bih0[tid]       + bhh0[tid];
    float ag = bih0[tid + 512] + bhh0[tid + 512];
    float ao = bih0[tid + 768] + bhh0[tid + 768];
    ai += dotf(Wih0 + (size_t)tid * 512, sx, 512);
    ag += dotf(Wih0 + (size_t)(tid + 512) * 512, sx, 512);
    ao += dotf(Wih0 + (size_t)(tid + 768) * 512, sx, 512);
    float c0 = sigm(ai) * tanhf(ag);
    float h1 = sigm(ao) * tanhf(c0);
    __syncthreads();
    sh[tid] = h1;
    __syncthreads();

    ai = bih1[tid]       + bhh1[tid];
    ag = bih1[tid + 512] + bhh1[tid + 512];
    ao = bih1[tid + 768] + bhh1[tid + 768];
    ai += dotf(Wih1 + (size_t)tid * 256, sh, 256);
    ag += dotf(Wih1 + (size_t)(tid + 512) * 256, sh, 256);
    ao += dotf(Wih1 + (size_t)(tid + 768) * 256, sh, 256);
    float c1 = sigm(ai) * tanhf(ag);
    float h2 = sigm(ao) * tanhf(c1);
    __syncthreads();
    sx[tid] = h2;
    __syncthreads();

    float o0 = bp[tid]       + dotf(Wp + (size_t)tid * 256, sx, 256);
    float o1 = bp[tid + 256] + dotf(Wp + (size_t)(tid + 256) * 256, sx, 256);
    out[g * 512 + tid]       = o0;
    out[g * 512 + 256 + tid] = o1;
}

// ---------------- launch ----------------

extern "C" void kernel_launch(void* const* d_in, const int* in_sizes, int n_in,
                              void* d_out, int out_size, void* d_ws, size_t ws_size,
                              hipStream_t stream) {
    const float* x     = (const float*)d_in[0];
    const int*   eidx  = (const int*)d_in[1];
    const int*   batch = (const int*)d_in[2];
    const float* W1 = (const float*)d_in[3];  const float* b1 = (const float*)d_in[4];
    const float* W2 = (const float*)d_in[5];  const float* b2 = (const float*)d_in[6];
    const float* W3 = (const float*)d_in[7];  const float* b3 = (const float*)d_in[8];
    const float* Wih0 = (const float*)d_in[9];
    const float* bih0 = (const float*)d_in[11];
    const float* bhh0 = (const float*)d_in[12];
    const float* Wih1 = (const float*)d_in[13];
    const float* bih1 = (const float*)d_in[15];
    const float* bhh1 = (const float*)d_in[16];
    const float* Wp = (const float*)d_in[17]; const float* bp = (const float*)d_in[18];
    float* out = (float*)d_out;

    const int N = in_sizes[0] / 32;
    const int E = in_sizes[1] / 2;
    const int* src = eidx;
    const int* dst = eidx + E;

    char* w = (char*)d_ws;
    auto alloc = [&](size_t bytes) {
        char* p = w;
        w += (bytes + 255) & ~(size_t)255;
        return p;
    };
    unsigned short* buf1 = (unsigned short*)alloc((size_t)N * 256 * 2);   // 51.2 MB
    unsigned short* buf2 = (unsigned short*)alloc((size_t)N * 256 * 2);   // 51.2 MB
    unsigned short* Wt1  = (unsigned short*)alloc(128 * 32 * 2);
    unsigned short* Wt2  = (unsigned short*)alloc(256 * 128 * 2);
    unsigned short* Wt3  = (unsigned short*)alloc(512 * 256 * 2);
    int*   indeg  = (int*)alloc((size_t)N * 4);
    int*   off    = (int*)alloc((size_t)(N + 1) * 4);
    int*   cursor = (int*)alloc((size_t)N * 4);
    float* dinv   = (float*)alloc((size_t)N * 4);
    int*   csrc   = (int*)alloc((size_t)E * 4);
    float* cw     = (float*)alloc((size_t)E * 4);
    int*   bsum   = (int*)alloc(256 * 4);
    int*   gstart = (int*)alloc(64 * 4);
    int*   gend   = (int*)alloc(64 * 4);
    float* pooled = (float*)alloc(64 * 512 * 4);

    hipMemsetAsync(indeg, 0, (size_t)N * 4, stream);
    hipMemsetAsync(cursor, 0, (size_t)N * 4, stream);
    hipMemsetAsync(gstart, 0, 64 * 4, stream);
    hipMemsetAsync(gend, 0, 64 * 4, stream);
    hipMemsetAsync(pooled, 0, 64 * 512 * 4, stream);

    k_count<<<(E + 255) / 256, 256, 0, stream>>>(dst, indeg, E);
    k_dinv<<<(N + 255) / 256, 256, 0, stream>>>(indeg, dinv, N);
    int nb = (N + 1023) / 1024;
    k_scan1<<<nb, 1024, 0, stream>>>(indeg, off, bsum, N);
    k_scan2<<<1, 64, 0, stream>>>(bsum, nb);
    k_scan3<<<(N + 1 + 1023) / 1024, 1024, 0, stream>>>(off, bsum, N, nb);
    k_fill<<<(E + 255) / 256, 256, 0, stream>>>(src, dst, dinv, off, cursor, csrc, cw, E);

    k_transpose<<<(32 * 128 + 255) / 256, 256, 0, stream>>>(W1, Wt1, 32, 128);
    k_transpose<<<(128 * 256 + 255) / 256, 256, 0, stream>>>(W2, Wt2, 128, 256);
    k_transpose<<<(256 * 512 + 255) / 256, 256, 0, stream>>>(W3, Wt3, 256, 512);
    k_bounds<<<(N + 255) / 256, 256, 0, stream>>>(batch, gstart, gend, N);

    int aggBlocks = (N + 3) / 4;                // one wave per node
    int rowTiles = (N + 63) / 64;

    // layer 1: agg(x fp32 [N,32]) -> buf1 bf16; gemm -> buf2 [N,128]
    k_agg2<32, float><<<aggBlocks, 256, 0, stream>>>(x, dinv, off, csrc, cw, buf1, N);
    k_gemm<32, 128, 0><<<rowTiles, 256, 0, stream>>>(buf1, Wt1, b1, buf2, nullptr, nullptr, N);
    // layer 2: agg -> buf1 [N,128]; gemm -> buf2 [N,256]
    k_agg2<128, unsigned short><<<aggBlocks, 256, 0, stream>>>(buf2, dinv, off, csrc, cw, buf1, N);
    k_gemm<128, 256, 0><<<rowTiles, 256, 0, stream>>>(buf1, Wt2, b2, buf2, nullptr, nullptr, N);
    // layer 3: agg -> buf1 [N,256]; gemm fused relu+pool
    k_agg2<256, unsigned short><<<aggBlocks, 256, 0, stream>>>(buf2, dinv, off, csrc, cw, buf1, N);
    k_gemm<256, 512, 1><<<rowTiles, 256, 0, stream>>>(buf1, Wt3, b3, nullptr, pooled, batch, N);

    k_head<<<64, 256, 0, stream>>>(pooled, gstart, gend,
                                   Wih0, bih0, bhh0, Wih1, bih1, bhh1, Wp, bp, out);
}

// Round 9
// 867.930 us; speedup vs baseline: 1.1577x; 1.0251x over previous
//
#include <hip/hip_runtime.h>
#include <math.h>
#include <type_traits>

// ---------- bf16 helpers (intermediate buffers only; I/O is fp32) ----------

__device__ __forceinline__ float bf2f(unsigned short u) {
    union { unsigned int i; float f; } v; v.i = ((unsigned int)u) << 16; return v.f;
}
__device__ __forceinline__ unsigned short f2bf(float f) {
    union { float f_; unsigned int i; } v; v.f_ = f;
    unsigned int x = v.i;
    return (unsigned short)((x + 0x7fffu + ((x >> 16) & 1u)) >> 16);  // RNE
}
__device__ __forceinline__ float sigm(float x) { return 1.f / (1.f + expf(-x)); }

typedef __attribute__((ext_vector_type(8))) short short8;
typedef __attribute__((ext_vector_type(4))) float f32x4;

// ---------------- CSR build ----------------

__global__ void k_count(const int* __restrict__ dst, int* __restrict__ indeg, int E) {
    int i = blockIdx.x * 256 + threadIdx.x;
    if (i < E) atomicAdd(&indeg[dst[i]], 1);
}

__global__ void k_dinv(const int* __restrict__ indeg, float* __restrict__ dinv, int N) {
    int i = blockIdx.x * 256 + threadIdx.x;
    if (i < N) dinv[i] = rsqrtf((float)indeg[i] + 1.0f);
}

__global__ __launch_bounds__(1024) void k_scan1(const int* __restrict__ in, int* __restrict__ out,
                                                int* __restrict__ bsum, int N) {
    __shared__ int sd[1024];
    int tid = threadIdx.x;
    int i = blockIdx.x * 1024 + tid;
    int v = (i < N) ? in[i] : 0;
    sd[tid] = v;
    __syncthreads();
    for (int s = 1; s < 1024; s <<= 1) {
        int t = (tid >= s) ? sd[tid - s] : 0;
        __syncthreads();
        sd[tid] += t;
        __syncthreads();
    }
    if (i < N) out[i] = sd[tid] - v;
    if (tid == 1023) bsum[blockIdx.x] = sd[1023];
}

__global__ void k_scan2(int* __restrict__ bsum, int nb) {
    if (threadIdx.x == 0 && blockIdx.x == 0) {
        int acc = 0;
        for (int b = 0; b < nb; ++b) { int t = bsum[b]; bsum[b] = acc; acc += t; }
        bsum[nb] = acc;
    }
}

__global__ __launch_bounds__(1024) void k_scan3(int* __restrict__ off, const int* __restrict__ bsum,
                                                int N, int nb) {
    int i = blockIdx.x * 1024 + threadIdx.x;
    if (i < N) off[i] += bsum[i >> 10];
    else if (i == N) off[N] = bsum[nb];
}

__global__ void k_fill(const int* __restrict__ src, const int* __restrict__ dst,
                       const float* __restrict__ dinv, const int* __restrict__ off,
                       int* __restrict__ cursor, int* __restrict__ csrc,
                       float* __restrict__ cw, int E) {
    int i = blockIdx.x * 256 + threadIdx.x;
    if (i >= E) return;
    int d = dst[i], s = src[i];
    int p = off[d] + atomicAdd(&cursor[d], 1);
    csrc[p] = s;
    cw[p] = dinv[s] * dinv[d];
}

// ---------------- weight transpose+convert: Wt[n][k] = bf16(W[k][n]) ----------------

__global__ void k_transpose(const float* __restrict__ W, unsigned short* __restrict__ Wt,
                            int K, int Nc) {
    int i = blockIdx.x * 256 + threadIdx.x;
    if (i < K * Nc) {
        int k = i / Nc, n = i - k * Nc;
        Wt[(size_t)n * K + k] = f2bf(W[i]);
    }
}

// ---------------- aggregation: one wave per node, branchless 8-deep prefetch ----

template <int F, typename T>
__global__ __launch_bounds__(256) void k_agg2(
        const T* __restrict__ Hin, const float* __restrict__ dinv,
        const int* __restrict__ off, const int* __restrict__ csrc,
        const float* __restrict__ cw, unsigned short* __restrict__ out, int N) {
    constexpr int R = (F >= 256) ? 4 : (F >= 128 ? 2 : 1);
    int wave = (int)((blockIdx.x * 256u + threadIdx.x) >> 6);
    int lane = threadIdx.x & 63;
    if (wave >= N) return;
    int fb = (F >= 64) ? lane * R : lane;
    bool act = fb < F;
    int s0 = off[wave], s1 = off[wave + 1];
    float dn = dinv[wave], sn = dn * dn;
    float acc[R];
    #pragma unroll
    for (int j = 0; j < R; ++j) acc[j] = 0.f;
    if (act) {
        const T* ps = Hin + (size_t)wave * F + fb;
        if constexpr (std::is_same_v<T, float>) {
            acc[0] = ps[0] * sn;
        } else if constexpr (R == 4) {
            ushort4 hv = *(const ushort4*)ps;
            acc[0] = bf2f(hv.x) * sn; acc[1] = bf2f(hv.y) * sn;
            acc[2] = bf2f(hv.z) * sn; acc[3] = bf2f(hv.w) * sn;
        } else {
            ushort2 hv = *(const ushort2*)ps;
            acc[0] = bf2f(hv.x) * sn; acc[1] = bf2f(hv.y) * sn;
        }
    }
    int last = s1 - 1;
    for (int e = s0; e < s1; e += 8) {
        int   idx[8];
        float wgt[8];
        #pragma unroll
        for (int j = 0; j < 8; ++j) {
            int ee = e + j;
            int ec = ee <= last ? ee : last;
            idx[j] = csrc[ec];
            wgt[j] = (ee <= last) ? cw[ec] : 0.f;
        }
        if (act) {
            if constexpr (std::is_same_v<T, float>) {
                float d0[8];
                #pragma unroll
                for (int j = 0; j < 8; ++j) d0[j] = Hin[(size_t)idx[j] * F + fb];
                #pragma unroll
                for (int j = 0; j < 8; ++j) acc[0] += d0[j] * wgt[j];
            } else if constexpr (R == 4) {
                ushort4 d0[8];
                #pragma unroll
                for (int j = 0; j < 8; ++j)
                    d0[j] = *(const ushort4*)(Hin + (size_t)idx[j] * F + fb);
                #pragma unroll
                for (int j = 0; j < 8; ++j) {
                    float w = wgt[j];
                    acc[0] += bf2f(d0[j].x) * w; acc[1] += bf2f(d0[j].y) * w;
                    acc[2] += bf2f(d0[j].z) * w; acc[3] += bf2f(d0[j].w) * w;
                }
            } else {
                ushort2 d0[8];
                #pragma unroll
                for (int j = 0; j < 8; ++j)
                    d0[j] = *(const ushort2*)(Hin + (size_t)idx[j] * F + fb);
                #pragma unroll
                for (int j = 0; j < 8; ++j) {
                    float w = wgt[j];
                    acc[0] += bf2f(d0[j].x) * w; acc[1] += bf2f(d0[j].y) * w;
                }
            }
        }
    }
    if (act) {
        unsigned short* pd = out + (size_t)wave * F + fb;
        if constexpr (R == 4) {
            ushort4 o; o.x = f2bf(acc[0]); o.y = f2bf(acc[1]);
            o.z = f2bf(acc[2]); o.w = f2bf(acc[3]);
            *(ushort4*)pd = o;
        } else if constexpr (R == 2) {
            ushort2 o; o.x = f2bf(acc[0]); o.y = f2bf(acc[1]);
            *(ushort2*)pd = o;
        } else {
            pd[0] = f2bf(acc[0]);
        }
    }
}

// ---------------- A-stationary MFMA GEMM v3: LDS-staged B, pipelined ----------------
// C = relu(A[M,K] @ W[K,NC] + b). One block per 64-row stripe. A-frags register-
// resident per wave. Per 64-col tile: B staged into LDS cooperatively (shared by
// all 4 waves, cuts L2 B-traffic 4x), global reads for tile t+1 issued during
// tile-t MFMA. LDS frag layout lane-contiguous (conflict-free b128).
// MFMA: A[m=lane&15][k=(lane>>4)*8+j], B same k; C/D col=lane&15, row=(lane>>4)*4+reg.
// POOL=1: relu + LDS pool epilogue.  NOTE: sbat/pacc init REQUIRES __syncthreads
// before any thread reads gmin/fast (r8 crash: wave 1-3 read garbage gmin ->
// negative pooled index -> OOB write).

template <int K, int NC, int POOL>
__global__ __launch_bounds__(256, 4) void k_gemm(
        const unsigned short* __restrict__ A, const unsigned short* __restrict__ Wt,
        const float* __restrict__ bias, unsigned short* __restrict__ C,
        float* __restrict__ pooled, const int* __restrict__ batch, int M) {
    constexpr int KST = K / 32;        // MFMA k-steps per tile
    constexpr int NT = NC / 64;        // column tiles
    constexpr int CH = K / 32;         // staged short8-chunks per thread (=KST)
    __shared__ short8 sB[4 * KST * 64];                 // 64 cols x K, frag layout
    __shared__ float pacc[POOL ? 2 : 1][POOL ? NC : 1];
    __shared__ int sbat[POOL ? 64 : 1];
    int tid = threadIdx.x;
    int lane = tid & 63, wv = tid >> 6;
    int r = lane & 15, q = lane >> 4;
    int rowB0 = blockIdx.x * 64;
    int row0 = rowB0 + wv * 16;

    int gmin = 0; bool fast = false;
    if (POOL) {
        if (tid < 64) {
            int rr = rowB0 + tid; if (rr > M - 1) rr = M - 1;
            sbat[tid] = batch[rr];
        }
        for (int i = tid; i < 2 * NC; i += 256) pacc[i / NC][i % NC] = 0.f;
        __syncthreads();               // REQUIRED: sbat visible to all waves
        gmin = sbat[0]; fast = (sbat[63] - gmin) <= 1;
    }

    // A-fragments, register-resident
    int rowA = row0 + r; if (rowA > M - 1) rowA = M - 1;
    const short8* Ap = (const short8*)(A + (size_t)rowA * K) + q;
    short8 aF[KST];
    #pragma unroll
    for (int kc = 0; kc < KST; ++kc) aF[kc] = Ap[kc * 4];

    // staging mapping: chunk c = i*256+tid; n = c&63 (col in tile), kq = c>>6
    int sn = tid & 63;                   // col within tile
    short8 stage[CH];
    {
        const short8* W8 = (const short8*)(Wt + (size_t)sn * K);
        #pragma unroll
        for (int i = 0; i < CH; ++i) {
            int kq = (i * 256 + tid) >> 6;
            stage[i] = W8[kq];
        }
    }
    int st = (sn >> 4) * (KST * 64) + (sn & 15);   // t'*KST*64 + r (add kc*64+q*16)

    for (int t = 0; t < NT; ++t) {
        __syncthreads();                 // LDS free (prev tile consumed)
        #pragma unroll
        for (int i = 0; i < CH; ++i) {
            int kq = (i * 256 + tid) >> 6;
            sB[st + (kq >> 2) * 64 + (kq & 3) * 16] = stage[i];
        }
        __syncthreads();
        if (t + 1 < NT) {                // prefetch next tile while MFMA runs
            const short8* W8 = (const short8*)(Wt + (size_t)((t + 1) * 64 + sn) * K);
            #pragma unroll
            for (int i = 0; i < CH; ++i) {
                int kq = (i * 256 + tid) >> 6;
                stage[i] = W8[kq];
            }
        }
        int col0 = t * 64;
        f32x4 acc[4] = {{0.f,0.f,0.f,0.f},{0.f,0.f,0.f,0.f},{0.f,0.f,0.f,0.f},{0.f,0.f,0.f,0.f}};
        #pragma unroll
        for (int kc = 0; kc < KST; ++kc) {
            #pragma unroll
            for (int tt = 0; tt < 4; ++tt) {
                short8 b = sB[(tt * KST + kc) * 64 + lane];
                acc[tt] = __builtin_amdgcn_mfma_f32_16x16x32_bf16(aF[kc], b, acc[tt], 0, 0, 0);
            }
        }
        #pragma unroll
        for (int tt = 0; tt < 4; ++tt) {
            int col = col0 + tt * 16 + r;
            float bv = bias[col];
            #pragma unroll
            for (int j = 0; j < 4; ++j) {
                int row = row0 + q * 4 + j;
                if (row < M) {
                    float v = fmaxf(acc[tt][j] + bv, 0.f);
                    if (POOL) {
                        int g = sbat[row - rowB0];
                        if (fast) atomicAdd(&pacc[g - gmin][col], v);
                        else      atomicAdd(&pooled[(size_t)g * NC + col], v);
                    } else {
                        C[(size_t)row * NC + col] = f2bf(v);
                    }
                }
            }
        }
    }
    if (POOL) {
        __syncthreads();
        if (fast) {
            for (int i = tid; i < 2 * NC; i += 256) {
                int gg = i / NC, col = i % NC;
                if (gmin + gg < 64 || gg == 0)
                    atomicAdd(&pooled[(size_t)(gmin + gg) * NC + col], pacc[gg][col]);
            }
        }
    }
}

// ---------------- graph segment bounds (batch sorted) ----------------

__global__ void k_bounds(const int* __restrict__ batch, int* __restrict__ gstart,
                         int* __restrict__ gend, int N) {
    int i = blockIdx.x * 256 + threadIdx.x;
    if (i >= N) return;
    int g = batch[i];
    if (i == 0 || batch[i - 1] != g) gstart[g] = i;
    if (i == N - 1 || batch[i + 1] != g) gend[g] = i + 1;
}

// ---------------- fused head (all fp32): mean + LSTM0 + LSTM1 + projection ----------------
// h0=c0=0 => gates = x @ Wih.T + bih + bhh; f-gate dead; c = i*g; h = o*tanh(c)

__device__ __forceinline__ float dotf(const float* __restrict__ w,
                                      const float* __restrict__ x, int K) {
    float a = 0.f;
    for (int k = 0; k < K; k += 4) {
        float4 wv = *(const float4*)(w + k);
        a += wv.x * x[k] + wv.y * x[k + 1] + wv.z * x[k + 2] + wv.w * x[k + 3];
    }
    return a;
}

__global__ __launch_bounds__(256) void k_head(
        const float* __restrict__ pooledSum,
        const int* __restrict__ gstart, const int* __restrict__ gend,
        const float* __restrict__ Wih0, const float* __restrict__ bih0,
        const float* __restrict__ bhh0,
        const float* __restrict__ Wih1, const float* __restrict__ bih1,
        const float* __restrict__ bhh1,
        const float* __restrict__ Wp, const float* __restrict__ bp,
        float* __restrict__ out) {
    __shared__ float sx[512];
    __shared__ float sh[256];
    int g = blockIdx.x, tid = threadIdx.x;
    float cnt = (float)(gend[g] - gstart[g]);
    float inv = 1.f / fmaxf(cnt, 1.f);
    sx[tid]       = pooledSum[g * 512 + tid] * inv;
    sx[tid + 256] = pooledSum[g * 512 + 256 + tid] * inv;
    __syncthreads();

    float ai = bih0[tid]       + bhh0[tid];
    float ag = bih0[tid + 512] + bhh0[tid + 512];
    float ao = bih0[tid + 768] + bhh0[tid + 768];
    ai += dotf(Wih0 + (size_t)tid * 512, sx, 512);
    ag += dotf(Wih0 + (size_t)(tid + 512) * 512, sx, 512);
    ao += dotf(Wih0 + (size_t)(tid + 768) * 512, sx, 512);
    float c0 = sigm(ai) * tanhf(ag);
    float h1 = sigm(ao) * tanhf(c0);
    __syncthreads();
    sh[tid] = h1;
    __syncthreads();

    ai = bih1[tid]       + bhh1[tid];
    ag = bih1[tid + 512] + bhh1[tid + 512];
    ao = bih1[tid + 768] + bhh1[tid + 768];
    ai += dotf(Wih1 + (size_t)tid * 256, sh, 256);
    ag += dotf(Wih1 + (size_t)(tid + 512) * 256, sh, 256);
    ao += dotf(Wih1 + (size_t)(tid + 768) * 256, sh, 256);
    float c1 = sigm(ai) * tanhf(ag);
    float h2 = sigm(ao) * tanhf(c1);
    __syncthreads();
    sx[tid] = h2;
    __syncthreads();

    float o0 = bp[tid]       + dotf(Wp + (size_t)tid * 256, sx, 256);
    float o1 = bp[tid + 256] + dotf(Wp + (size_t)(tid + 256) * 256, sx, 256);
    out[g * 512 + tid]       = o0;
    out[g * 512 + 256 + tid] = o1;
}

// ---------------- launch ----------------

extern "C" void kernel_launch(void* const* d_in, const int* in_sizes, int n_in,
                              void* d_out, int out_size, void* d_ws, size_t ws_size,
                              hipStream_t stream) {
    const float* x     = (const float*)d_in[0];
    const int*   eidx  = (const int*)d_in[1];
    const int*   batch = (const int*)d_in[2];
    const float* W1 = (const float*)d_in[3];  const float* b1 = (const float*)d_in[4];
    const float* W2 = (const float*)d_in[5];  const float* b2 = (const float*)d_in[6];
    const float* W3 = (const float*)d_in[7];  const float* b3 = (const float*)d_in[8];
    const float* Wih0 = (const float*)d_in[9];
    const float* bih0 = (const float*)d_in[11];
    const float* bhh0 = (const float*)d_in[12];
    const float* Wih1 = (const float*)d_in[13];
    const float* bih1 = (const float*)d_in[15];
    const float* bhh1 = (const float*)d_in[16];
    const float* Wp = (const float*)d_in[17]; const float* bp = (const float*)d_in[18];
    float* out = (float*)d_out;

    const int N = in_sizes[0] / 32;
    const int E = in_sizes[1] / 2;
    const int* src = eidx;
    const int* dst = eidx + E;

    char* w = (char*)d_ws;
    auto alloc = [&](size_t bytes) {
        char* p = w;
        w += (bytes + 255) & ~(size_t)255;
        return p;
    };
    unsigned short* buf1 = (unsigned short*)alloc((size_t)N * 256 * 2);   // 51.2 MB
    unsigned short* buf2 = (unsigned short*)alloc((size_t)N * 256 * 2);   // 51.2 MB
    unsigned short* Wt1  = (unsigned short*)alloc(128 * 32 * 2);
    unsigned short* Wt2  = (unsigned short*)alloc(256 * 128 * 2);
    unsigned short* Wt3  = (unsigned short*)alloc(512 * 256 * 2);
    int*   indeg  = (int*)alloc((size_t)N * 4);
    int*   off    = (int*)alloc((size_t)(N + 1) * 4);
    int*   cursor = (int*)alloc((size_t)N * 4);
    float* dinv   = (float*)alloc((size_t)N * 4);
    int*   csrc   = (int*)alloc((size_t)E * 4);
    float* cw     = (float*)alloc((size_t)E * 4);
    int*   bsum   = (int*)alloc(256 * 4);
    int*   gstart = (int*)alloc(64 * 4);
    int*   gend   = (int*)alloc(64 * 4);
    float* pooled = (float*)alloc(64 * 512 * 4);

    hipMemsetAsync(indeg, 0, (size_t)N * 4, stream);
    hipMemsetAsync(cursor, 0, (size_t)N * 4, stream);
    hipMemsetAsync(gstart, 0, 64 * 4, stream);
    hipMemsetAsync(gend, 0, 64 * 4, stream);
    hipMemsetAsync(pooled, 0, 64 * 512 * 4, stream);

    k_count<<<(E + 255) / 256, 256, 0, stream>>>(dst, indeg, E);
    k_dinv<<<(N + 255) / 256, 256, 0, stream>>>(indeg, dinv, N);
    int nb = (N + 1023) / 1024;
    k_scan1<<<nb, 1024, 0, stream>>>(indeg, off, bsum, N);
    k_scan2<<<1, 64, 0, stream>>>(bsum, nb);
    k_scan3<<<(N + 1 + 1023) / 1024, 1024, 0, stream>>>(off, bsum, N, nb);
    k_fill<<<(E + 255) / 256, 256, 0, stream>>>(src, dst, dinv, off, cursor, csrc, cw, E);

    k_transpose<<<(32 * 128 + 255) / 256, 256, 0, stream>>>(W1, Wt1, 32, 128);
    k_transpose<<<(128 * 256 + 255) / 256, 256, 0, stream>>>(W2, Wt2, 128, 256);
    k_transpose<<<(256 * 512 + 255) / 256, 256, 0, stream>>>(W3, Wt3, 256, 512);
    k_bounds<<<(N + 255) / 256, 256, 0, stream>>>(batch, gstart, gend, N);

    int aggBlocks = (N + 3) / 4;                // one wave per node
    int rowTiles = (N + 63) / 64;

    // layer 1: agg(x fp32 [N,32]) -> buf1 bf16; gemm -> buf2 [N,128]
    k_agg2<32, float><<<aggBlocks, 256, 0, stream>>>(x, dinv, off, csrc, cw, buf1, N);
    k_gemm<32, 128, 0><<<rowTiles, 256, 0, stream>>>(buf1, Wt1, b1, buf2, nullptr, nullptr, N);
    // layer 2: agg -> buf1 [N,128]; gemm -> buf2 [N,256]
    k_agg2<128, unsigned short><<<aggBlocks, 256, 0, stream>>>(buf2, dinv, off, csrc, cw, buf1, N);
    k_gemm<128, 256, 0><<<rowTiles, 256, 0, stream>>>(buf1, Wt2, b2, buf2, nullptr, nullptr, N);
    // layer 3: agg -> buf1 [N,256]; gemm fused relu+pool
    k_agg2<256, unsigned short><<<aggBlocks, 256, 0, stream>>>(buf2, dinv, off, csrc, cw, buf1, N);
    k_gemm<256, 512, 1><<<rowTiles, 256, 0, stream>>>(buf1, Wt3, b3, nullptr, pooled, batch, N);

    k_head<<<64, 256, 0, stream>>>(pooled, gstart, gend,
                                   Wih0, bih0, bhh0, Wih1, bih1, bhh1, Wp, bp, out);
}